// Round 4
// baseline (104.526 us; speedup 1.0000x reference)
//
#include <hip/hip_runtime.h>

#define TT 768
#define KD 512
#define NC 1024
#define RLN2_2 2.8853900817779268f   // 2/ln(2)

typedef short short8 __attribute__((ext_vector_type(8)));
typedef float f32x4  __attribute__((ext_vector_type(4)));

__device__ __forceinline__ float fast_exp2(float x) {
#if __has_builtin(__builtin_amdgcn_exp2f)
    return __builtin_amdgcn_exp2f(x);
#else
    return exp2f(x);
#endif
}
__device__ __forceinline__ float fast_rcp(float x) {
#if __has_builtin(__builtin_amdgcn_rcpf)
    return __builtin_amdgcn_rcpf(x);
#else
    return 1.0f / x;
#endif
}
__device__ __forceinline__ float fast_tanh(float x) {
    float e = fast_exp2(x * RLN2_2);
    return fmaf(-2.0f, fast_rcp(e + 1.0f), 1.0f);
}
__device__ __forceinline__ ushort f2bf(float f) {   // RNE f32->bf16
    uint u = __float_as_uint(f);
    u += 0x7fff + ((u >> 16) & 1);
    return (ushort)(u >> 16);
}

// ---------------------------------------------------------------------------
// Prep: x->bf16; foh/fom -> [c][k] bf16; hid2 -> [n][k] bf16 (transposes)
// ---------------------------------------------------------------------------
__global__ __launch_bounds__(256) void k_prep(
    const float* __restrict__ x, const float* __restrict__ foh,
    const float* __restrict__ fom, const float* __restrict__ hid2,
    ushort* __restrict__ xb, ushort* __restrict__ b1t, ushort* __restrict__ h2t)
{
    const int b = blockIdx.x, t = threadIdx.x;
    if (b < 96) {
        int base = b * 4096 + t * 16;
        #pragma unroll
        for (int q = 0; q < 4; ++q) {
            float4 v = *(const float4*)&x[base + q * 4];
            ushort4 o; o.x = f2bf(v.x); o.y = f2bf(v.y); o.z = f2bf(v.z); o.w = f2bf(v.w);
            *(ushort4*)&xb[base + q * 4] = o;
        }
        return;
    }
    __shared__ float tile[64][65];
    const float* src; ushort* dst; int R, C, r0, c0;
    if (b < 160)      { int bb = b - 96;  src = foh;  dst = b1t;             R = 512;  C = 512; r0 = (bb >> 3) * 64; c0 = (bb & 7) * 64; }
    else if (b < 224) { int bb = b - 160; src = fom;  dst = b1t + 512 * 512; R = 512;  C = 512; r0 = (bb >> 3) * 64; c0 = (bb & 7) * 64; }
    else              { int bb = b - 224; src = hid2; dst = h2t;             R = 1024; C = 512; r0 = (bb >> 3) * 64; c0 = (bb & 7) * 64; }
    const int ty = t >> 4, tx = t & 15;
    #pragma unroll
    for (int q = 0; q < 4; ++q) {
        float4 v = *(const float4*)&src[(r0 + ty + q * 16) * C + c0 + tx * 4];
        tile[ty + q * 16][tx * 4 + 0] = v.x;
        tile[ty + q * 16][tx * 4 + 1] = v.y;
        tile[ty + q * 16][tx * 4 + 2] = v.z;
        tile[ty + q * 16][tx * 4 + 3] = v.w;
    }
    __syncthreads();
    #pragma unroll
    for (int q = 0; q < 4; ++q) {
        int cl = ty + q * 16;
        ushort4 o;
        o.x = f2bf(tile[tx * 4 + 0][cl]);
        o.y = f2bf(tile[tx * 4 + 1][cl]);
        o.z = f2bf(tile[tx * 4 + 2][cl]);
        o.w = f2bf(tile[tx * 4 + 3][cl]);
        *(ushort4*)&dst[(c0 + cl) * R + r0 + tx * 4] = o;
    }
}

// ---------------------------------------------------------------------------
// GEMM1 (MFMA bf16): act = tanh(xb @ b1t^T + catBias), bf16 out
// ---------------------------------------------------------------------------
__global__ __launch_bounds__(256) void k_gemm1(
    const ushort* __restrict__ xb, const ushort* __restrict__ b1t,
    const float* __restrict__ catBias, ushort* __restrict__ act)
{
    const int t = threadIdx.x;
    const int wave = t >> 6, lane = t & 63;
    const int wr = wave >> 1, wc = wave & 1;
    const int n0 = blockIdx.x * 64 + wc * 32;
    const int m0 = blockIdx.y * 64 + wr * 32;
    const int lrow = lane & 15, lk = (lane >> 4) * 8;

    const ushort* pa0 = &xb[(m0 + lrow) * KD + lk];
    const ushort* pa1 = pa0 + 16 * KD;
    const ushort* pb0 = &b1t[(n0 + lrow) * KD + lk];
    const ushort* pb1 = pb0 + 16 * KD;

    f32x4 acc[2][2] = {};
    #pragma unroll 4
    for (int k0 = 0; k0 < KD; k0 += 32) {
        short8 a0 = *(const short8*)(pa0 + k0);
        short8 a1 = *(const short8*)(pa1 + k0);
        short8 b0 = *(const short8*)(pb0 + k0);
        short8 b1 = *(const short8*)(pb1 + k0);
        acc[0][0] = __builtin_amdgcn_mfma_f32_16x16x32_bf16(a0, b0, acc[0][0], 0, 0, 0);
        acc[0][1] = __builtin_amdgcn_mfma_f32_16x16x32_bf16(a0, b1, acc[0][1], 0, 0, 0);
        acc[1][0] = __builtin_amdgcn_mfma_f32_16x16x32_bf16(a1, b0, acc[1][0], 0, 0, 0);
        acc[1][1] = __builtin_amdgcn_mfma_f32_16x16x32_bf16(a1, b1, acc[1][1], 0, 0, 0);
    }
    const int crow = (lane >> 4) * 4, ccol = lane & 15;
    #pragma unroll
    for (int nf = 0; nf < 2; ++nf) {
        int col = n0 + nf * 16 + ccol;
        float cb = catBias[col];
        #pragma unroll
        for (int mf = 0; mf < 2; ++mf) {
            #pragma unroll
            for (int r = 0; r < 4; ++r) {
                int row = m0 + mf * 16 + crow + r;
                act[row * NC + col] = f2bf(fast_tanh(acc[mf][nf][r] + cb));
            }
        }
    }
}

// ---------------------------------------------------------------------------
// GEMM2 (MFMA bf16) + exp epilogue -> pw = EA | EM (f32)
// ---------------------------------------------------------------------------
__global__ __launch_bounds__(256) void k_gemm2(
    const ushort* __restrict__ act, const ushort* __restrict__ h2t,
    const float* __restrict__ hid2Bias, float* __restrict__ pw)
{
    const int t = threadIdx.x;
    const int wave = t >> 6, lane = t & 63;
    const int wr = wave >> 1, wc = wave & 1;
    const int n0 = blockIdx.x * 64 + wc * 32;
    const int m0 = blockIdx.y * 64 + wr * 32;
    const bool top = (blockIdx.x < 8);
    const int koff = top ? 0 : 512;
    const int nc0  = top ? n0 : n0 - 512;
    const int lrow = lane & 15, lk = (lane >> 4) * 8;

    const ushort* pa0 = &act[(m0 + lrow) * NC + koff + lk];
    const ushort* pa1 = pa0 + 16 * NC;
    const ushort* pb0 = &h2t[(nc0 + lrow) * NC + koff + lk];
    const ushort* pb1 = pb0 + 16 * NC;

    f32x4 acc[2][2] = {};
    #pragma unroll 4
    for (int k0 = 0; k0 < KD; k0 += 32) {
        short8 a0 = *(const short8*)(pa0 + k0);
        short8 a1 = *(const short8*)(pa1 + k0);
        short8 b0 = *(const short8*)(pb0 + k0);
        short8 b1 = *(const short8*)(pb1 + k0);
        acc[0][0] = __builtin_amdgcn_mfma_f32_16x16x32_bf16(a0, b0, acc[0][0], 0, 0, 0);
        acc[0][1] = __builtin_amdgcn_mfma_f32_16x16x32_bf16(a0, b1, acc[0][1], 0, 0, 0);
        acc[1][0] = __builtin_amdgcn_mfma_f32_16x16x32_bf16(a1, b0, acc[1][0], 0, 0, 0);
        acc[1][1] = __builtin_amdgcn_mfma_f32_16x16x32_bf16(a1, b1, acc[1][1], 0, 0, 0);
    }
    const int crow = (lane >> 4) * 4, ccol = lane & 15;
    #pragma unroll
    for (int nf = 0; nf < 2; ++nf) {
        int col = n0 + nf * 16 + ccol;
        float hb = top ? hid2Bias[col] : 0.0f;
        #pragma unroll
        for (int mf = 0; mf < 2; ++mf) {
            #pragma unroll
            for (int r = 0; r < 4; ++r) {
                int row = m0 + mf * 16 + crow + r;
                pw[row * NC + col] = fast_exp2(RLN2_2 * (acc[mf][nf][r] + hb));
            }
        }
    }
}

// ---------------------------------------------------------------------------
// Pairwise: out[i][j] = (outBias + sum w) - 2*sum_h w[h]/(1 + EA[i,h]*EM[j,h])
// Block = 128 thr (2 waves), tile 16i x 32j; wave wv sums h in [wv*256, +256).
// Per-thread micro: 2i x 4j, batched reciprocal over the 4 j's (1 rcp / 4).
// Em stored with 4x8 row permutation -> conflict-free strided reads.
// Grid = 1152 (8 | 1152 for XCD swizzle), ~10 waves/CU, no in-loop barriers.
// ---------------------------------------------------------------------------
__global__ __launch_bounds__(128) void k_pair(
    const float* __restrict__ pw, const float* __restrict__ w,
    const float* __restrict__ outBias, float* __restrict__ out)
{
    __shared__ float EaS[2][16][68];
    __shared__ float EmS[2][32][68];
    __shared__ float partial[512];

    const int t = threadIdx.x;
    const int wv = t >> 6, lane = t & 63;
    const int bid = blockIdx.x;
    const int sw = (bid & 7) * 144 + (bid >> 3);     // XCD swizzle
    const int it = sw / 24, jt = sw - it * 24;
    const int i0 = it * 16, j0 = jt * 32;
    const int ti = lane >> 3, tj = lane & 7;

    const int hbase = __builtin_amdgcn_readfirstlane(wv * 256);

    // staging geometry
    const int arow = lane >> 2;                      // Ea row 0..15
    const int acol = (lane & 3) * 16;                // float col within 64-h chunk
    const int prm  = lane >> 1;                      // Em physical row 0..31
    const int lrm  = (prm & 7) * 4 + (prm >> 3);     // logical j row
    const int mcol = (lane & 1) * 32;

    const float* srcA = &pw[(i0 + arow) * NC + hbase + acol];
    const float* srcM = &pw[(j0 + lrm) * NC + 512 + hbase + mcol];

    float4 fa[4], fm[8];
    #pragma unroll
    for (int q = 0; q < 4; ++q) fa[q] = *(const float4*)(srcA + q * 4);
    #pragma unroll
    for (int q = 0; q < 8; ++q) fm[q] = *(const float4*)(srcM + q * 4);

    float4 acc0 = {0.f, 0.f, 0.f, 0.f};
    float4 acc1 = {0.f, 0.f, 0.f, 0.f};

    #pragma unroll 1
    for (int c = 0; c < 4; ++c) {
        const int hh = c * 64;
        // stage current chunk (single buffer; wave-internal DS ordering)
        #pragma unroll
        for (int q = 0; q < 4; ++q) *(float4*)&EaS[wv][arow][acol + q * 4] = fa[q];
        #pragma unroll
        for (int q = 0; q < 8; ++q) *(float4*)&EmS[wv][prm][mcol + q * 4] = fm[q];
        // prefetch next chunk into regs (overlaps compute)
        if (c < 3) {
            #pragma unroll
            for (int q = 0; q < 4; ++q) fa[q] = *(const float4*)(srcA + hh + 64 + q * 4);
            #pragma unroll
            for (int q = 0; q < 8; ++q) fm[q] = *(const float4*)(srcM + hh + 64 + q * 4);
        }
        #pragma unroll
        for (int hq = 0; hq < 16; ++hq) {
            float4 e0 = *(const float4*)&EaS[wv][2 * ti    ][hq * 4];
            float4 e1 = *(const float4*)&EaS[wv][2 * ti + 1][hq * 4];
            float4 f0 = *(const float4*)&EmS[wv][tj        ][hq * 4];
            float4 f1 = *(const float4*)&EmS[wv][tj + 8    ][hq * 4];
            float4 f2 = *(const float4*)&EmS[wv][tj + 16   ][hq * 4];
            float4 f3 = *(const float4*)&EmS[wv][tj + 24   ][hq * 4];
            const float* e0p = (const float*)&e0;
            const float* e1p = (const float*)&e1;
            const float* f0p = (const float*)&f0;
            const float* f1p = (const float*)&f1;
            const float* f2p = (const float*)&f2;
            const float* f3p = (const float*)&f3;
            float* a0p = (float*)&acc0;
            float* a1p = (float*)&acc1;
            #pragma unroll
            for (int h = 0; h < 4; ++h) {
                const float wh = w[hbase + hh + hq * 4 + h];
                const float ff0 = f0p[h], ff1 = f1p[h], ff2 = f2p[h], ff3 = f3p[h];
                {   // i2 = 0
                    float e  = e0p[h];
                    float d0 = fmaf(e, ff0, 1.f), d1 = fmaf(e, ff1, 1.f);
                    float d2 = fmaf(e, ff2, 1.f), d3 = fmaf(e, ff3, 1.f);
                    float d01 = d0 * d1, d23 = d2 * d3;
                    float r = fast_rcp(d01 * d23);
                    float rw01 = r * d23 * wh, rw23 = r * d01 * wh;
                    a0p[0] = fmaf(rw01, d1, a0p[0]);
                    a0p[1] = fmaf(rw01, d0, a0p[1]);
                    a0p[2] = fmaf(rw23, d3, a0p[2]);
                    a0p[3] = fmaf(rw23, d2, a0p[3]);
                }
                {   // i2 = 1
                    float e  = e1p[h];
                    float d0 = fmaf(e, ff0, 1.f), d1 = fmaf(e, ff1, 1.f);
                    float d2 = fmaf(e, ff2, 1.f), d3 = fmaf(e, ff3, 1.f);
                    float d01 = d0 * d1, d23 = d2 * d3;
                    float r = fast_rcp(d01 * d23);
                    float rw01 = r * d23 * wh, rw23 = r * d01 * wh;
                    a1p[0] = fmaf(rw01, d1, a1p[0]);
                    a1p[1] = fmaf(rw01, d0, a1p[1]);
                    a1p[2] = fmaf(rw23, d3, a1p[2]);
                    a1p[3] = fmaf(rw23, d2, a1p[3]);
                }
            }
        }
    }

    // combine the two waves' h-halves
    if (wv == 1) {
        float* a0p = (float*)&acc0;
        float* a1p = (float*)&acc1;
        #pragma unroll
        for (int q = 0; q < 4; ++q) partial[lane * 8 + q]     = a0p[q];
        #pragma unroll
        for (int q = 0; q < 4; ++q) partial[lane * 8 + 4 + q] = a1p[q];
    }
    __syncthreads();
    if (wv == 0) {
        float4 wa = *(const float4*)&w[lane * 8];
        float4 wb = *(const float4*)&w[lane * 8 + 4];
        float lsum = (wa.x + wa.y + wa.z + wa.w) + (wb.x + wb.y + wb.z + wb.w);
        #pragma unroll
        for (int d = 1; d < 64; d <<= 1) lsum += __shfl_xor(lsum, d, 64);
        const float base = lsum + outBias[0];
        const float* a0p = (const float*)&acc0;
        const float* a1p = (const float*)&acc1;
        const int gi = i0 + 2 * ti, gj = j0 + 4 * tj;
        float4 o0, o1;
        float* o0p = (float*)&o0;
        float* o1p = (float*)&o1;
        #pragma unroll
        for (int q = 0; q < 4; ++q) {
            o0p[q] = fmaf(-2.f, a0p[q] + partial[lane * 8 + q],     base);
            o1p[q] = fmaf(-2.f, a1p[q] + partial[lane * 8 + 4 + q], base);
        }
        *(float4*)&out[gi * TT + gj]       = o0;
        *(float4*)&out[(gi + 1) * TT + gj] = o1;
    }
}

extern "C" void kernel_launch(void* const* d_in, const int* in_sizes, int n_in,
                              void* d_out, int out_size, void* d_ws, size_t ws_size,
                              hipStream_t stream) {
    const float* x        = (const float*)d_in[0];
    const float* foh      = (const float*)d_in[1];
    const float* fom      = (const float*)d_in[2];
    const float* catBias  = (const float*)d_in[3];
    const float* hid2     = (const float*)d_in[4];
    const float* hid2Bias = (const float*)d_in[5];
    const float* outLayer = (const float*)d_in[6];
    const float* outBias  = (const float*)d_in[7];
    float* out = (float*)d_out;

    char* wsb = (char*)d_ws;
    float*  pw  = (float*)(wsb);                        // 768*1024*4 = 3145728
    ushort* act = (ushort*)(wsb + 3145728);             // 768*1024*2
    ushort* xb  = (ushort*)(wsb + 4718592);             // 768*512*2
    ushort* b1t = (ushort*)(wsb + 5505024);             // 1024*512*2
    ushort* h2t = (ushort*)(wsb + 6553600);             // 512*1024*2

    k_prep <<<dim3(352),    256, 0, stream>>>(x, foh, fom, hid2, xb, b1t, h2t);
    k_gemm1<<<dim3(16, 12), 256, 0, stream>>>(xb, b1t, catBias, act);
    k_gemm2<<<dim3(16, 12), 256, 0, stream>>>(act, h2t, hid2Bias, pw);
    k_pair <<<dim3(1152),   128, 0, stream>>>(pw, outLayer, outBias, out);
}

// Round 5
// 97.937 us; speedup vs baseline: 1.0673x; 1.0673x over previous
//
#include <hip/hip_runtime.h>

#define TT 768
#define KD 512
#define NC 1024
#define RLN2_2 2.8853900817779268f   // 2/ln(2)

typedef short short8 __attribute__((ext_vector_type(8)));
typedef float f32x4  __attribute__((ext_vector_type(4)));

__device__ __forceinline__ float fast_exp2(float x) {
#if __has_builtin(__builtin_amdgcn_exp2f)
    return __builtin_amdgcn_exp2f(x);
#else
    return exp2f(x);
#endif
}
__device__ __forceinline__ float fast_rcp(float x) {
#if __has_builtin(__builtin_amdgcn_rcpf)
    return __builtin_amdgcn_rcpf(x);
#else
    return 1.0f / x;
#endif
}
__device__ __forceinline__ float fast_tanh(float x) {
    float e = fast_exp2(x * RLN2_2);
    return fmaf(-2.0f, fast_rcp(e + 1.0f), 1.0f);
}
__device__ __forceinline__ ushort f2bf(float f) {   // RNE f32->bf16
    uint u = __float_as_uint(f);
    u += 0x7fff + ((u >> 16) & 1);
    return (ushort)(u >> 16);
}

// ---------------------------------------------------------------------------
// Prep: x->bf16; foh/fom -> [c][k] bf16; hid2 -> [n][k] bf16 (transposes)
// ---------------------------------------------------------------------------
__global__ __launch_bounds__(256) void k_prep(
    const float* __restrict__ x, const float* __restrict__ foh,
    const float* __restrict__ fom, const float* __restrict__ hid2,
    ushort* __restrict__ xb, ushort* __restrict__ b1t, ushort* __restrict__ h2t)
{
    const int b = blockIdx.x, t = threadIdx.x;
    if (b < 96) {
        int base = b * 4096 + t * 16;
        #pragma unroll
        for (int q = 0; q < 4; ++q) {
            float4 v = *(const float4*)&x[base + q * 4];
            ushort4 o; o.x = f2bf(v.x); o.y = f2bf(v.y); o.z = f2bf(v.z); o.w = f2bf(v.w);
            *(ushort4*)&xb[base + q * 4] = o;
        }
        return;
    }
    __shared__ float tile[64][65];
    const float* src; ushort* dst; int R, C, r0, c0;
    if (b < 160)      { int bb = b - 96;  src = foh;  dst = b1t;             R = 512;  C = 512; r0 = (bb >> 3) * 64; c0 = (bb & 7) * 64; }
    else if (b < 224) { int bb = b - 160; src = fom;  dst = b1t + 512 * 512; R = 512;  C = 512; r0 = (bb >> 3) * 64; c0 = (bb & 7) * 64; }
    else              { int bb = b - 224; src = hid2; dst = h2t;             R = 1024; C = 512; r0 = (bb >> 3) * 64; c0 = (bb & 7) * 64; }
    const int ty = t >> 4, tx = t & 15;
    #pragma unroll
    for (int q = 0; q < 4; ++q) {
        float4 v = *(const float4*)&src[(r0 + ty + q * 16) * C + c0 + tx * 4];
        tile[ty + q * 16][tx * 4 + 0] = v.x;
        tile[ty + q * 16][tx * 4 + 1] = v.y;
        tile[ty + q * 16][tx * 4 + 2] = v.z;
        tile[ty + q * 16][tx * 4 + 3] = v.w;
    }
    __syncthreads();
    #pragma unroll
    for (int q = 0; q < 4; ++q) {
        int cl = ty + q * 16;
        ushort4 o;
        o.x = f2bf(tile[tx * 4 + 0][cl]);
        o.y = f2bf(tile[tx * 4 + 1][cl]);
        o.z = f2bf(tile[tx * 4 + 2][cl]);
        o.w = f2bf(tile[tx * 4 + 3][cl]);
        *(ushort4*)&dst[(c0 + cl) * R + r0 + tx * 4] = o;
    }
}

// ---------------------------------------------------------------------------
// GEMM1 (MFMA bf16): act = tanh(xb @ b1t^T + catBias), bf16 out
// ---------------------------------------------------------------------------
__global__ __launch_bounds__(256) void k_gemm1(
    const ushort* __restrict__ xb, const ushort* __restrict__ b1t,
    const float* __restrict__ catBias, ushort* __restrict__ act)
{
    const int t = threadIdx.x;
    const int wave = t >> 6, lane = t & 63;
    const int wr = wave >> 1, wc = wave & 1;
    const int n0 = blockIdx.x * 64 + wc * 32;
    const int m0 = blockIdx.y * 64 + wr * 32;
    const int lrow = lane & 15, lk = (lane >> 4) * 8;

    const ushort* pa0 = &xb[(m0 + lrow) * KD + lk];
    const ushort* pa1 = pa0 + 16 * KD;
    const ushort* pb0 = &b1t[(n0 + lrow) * KD + lk];
    const ushort* pb1 = pb0 + 16 * KD;

    f32x4 acc[2][2] = {};
    #pragma unroll 4
    for (int k0 = 0; k0 < KD; k0 += 32) {
        short8 a0 = *(const short8*)(pa0 + k0);
        short8 a1 = *(const short8*)(pa1 + k0);
        short8 b0 = *(const short8*)(pb0 + k0);
        short8 b1 = *(const short8*)(pb1 + k0);
        acc[0][0] = __builtin_amdgcn_mfma_f32_16x16x32_bf16(a0, b0, acc[0][0], 0, 0, 0);
        acc[0][1] = __builtin_amdgcn_mfma_f32_16x16x32_bf16(a0, b1, acc[0][1], 0, 0, 0);
        acc[1][0] = __builtin_amdgcn_mfma_f32_16x16x32_bf16(a1, b0, acc[1][0], 0, 0, 0);
        acc[1][1] = __builtin_amdgcn_mfma_f32_16x16x32_bf16(a1, b1, acc[1][1], 0, 0, 0);
    }
    const int crow = (lane >> 4) * 4, ccol = lane & 15;
    #pragma unroll
    for (int nf = 0; nf < 2; ++nf) {
        int col = n0 + nf * 16 + ccol;
        float cb = catBias[col];
        #pragma unroll
        for (int mf = 0; mf < 2; ++mf) {
            #pragma unroll
            for (int r = 0; r < 4; ++r) {
                int row = m0 + mf * 16 + crow + r;
                act[row * NC + col] = f2bf(fast_tanh(acc[mf][nf][r] + cb));
            }
        }
    }
}

// ---------------------------------------------------------------------------
// GEMM2 (MFMA bf16) + exp epilogue -> pw = EA | EM (f32)
// ---------------------------------------------------------------------------
__global__ __launch_bounds__(256) void k_gemm2(
    const ushort* __restrict__ act, const ushort* __restrict__ h2t,
    const float* __restrict__ hid2Bias, float* __restrict__ pw)
{
    const int t = threadIdx.x;
    const int wave = t >> 6, lane = t & 63;
    const int wr = wave >> 1, wc = wave & 1;
    const int n0 = blockIdx.x * 64 + wc * 32;
    const int m0 = blockIdx.y * 64 + wr * 32;
    const bool top = (blockIdx.x < 8);
    const int koff = top ? 0 : 512;
    const int nc0  = top ? n0 : n0 - 512;
    const int lrow = lane & 15, lk = (lane >> 4) * 8;

    const ushort* pa0 = &act[(m0 + lrow) * NC + koff + lk];
    const ushort* pa1 = pa0 + 16 * NC;
    const ushort* pb0 = &h2t[(nc0 + lrow) * NC + koff + lk];
    const ushort* pb1 = pb0 + 16 * NC;

    f32x4 acc[2][2] = {};
    #pragma unroll 4
    for (int k0 = 0; k0 < KD; k0 += 32) {
        short8 a0 = *(const short8*)(pa0 + k0);
        short8 a1 = *(const short8*)(pa1 + k0);
        short8 b0 = *(const short8*)(pb0 + k0);
        short8 b1 = *(const short8*)(pb1 + k0);
        acc[0][0] = __builtin_amdgcn_mfma_f32_16x16x32_bf16(a0, b0, acc[0][0], 0, 0, 0);
        acc[0][1] = __builtin_amdgcn_mfma_f32_16x16x32_bf16(a0, b1, acc[0][1], 0, 0, 0);
        acc[1][0] = __builtin_amdgcn_mfma_f32_16x16x32_bf16(a1, b0, acc[1][0], 0, 0, 0);
        acc[1][1] = __builtin_amdgcn_mfma_f32_16x16x32_bf16(a1, b1, acc[1][1], 0, 0, 0);
    }
    const int crow = (lane >> 4) * 4, ccol = lane & 15;
    #pragma unroll
    for (int nf = 0; nf < 2; ++nf) {
        int col = n0 + nf * 16 + ccol;
        float hb = top ? hid2Bias[col] : 0.0f;
        #pragma unroll
        for (int mf = 0; mf < 2; ++mf) {
            #pragma unroll
            for (int r = 0; r < 4; ++r) {
                int row = m0 + mf * 16 + crow + r;
                pw[row * NC + col] = fast_exp2(RLN2_2 * (acc[mf][nf][r] + hb));
            }
        }
    }
}

// ---------------------------------------------------------------------------
// Pairwise: out[i][j] = (outBias + sum w) - 2*sum_h w[h]/(1 + EA[i,h]*EM[j,h])
// Block = 128 thr (2 waves), tile 16i x 32j; wave wv sums h in [wv*256,+256).
// Micro 2i x 4j, batched reciprocal (1 rcp / 4 evals).
// w staged in LDS (uniform b128 broadcast reads -- the r4 s_load fix).
// Em stored with 4x8 row permutation -> conflict-free strided reads.
// Grid = 1152, LDS 28160 B -> 5 blocks/CU = 10 waves/CU; no in-loop barriers.
// ---------------------------------------------------------------------------
__global__ __launch_bounds__(128) void k_pair(
    const float* __restrict__ pw, const float* __restrict__ w,
    const float* __restrict__ outBias, float* __restrict__ out)
{
    __shared__ float EaS[2][16][68];
    __shared__ float EmS[2][32][68];
    __shared__ float wl[512];

    const int t = threadIdx.x;
    const int wv = t >> 6, lane = t & 63;
    const int bid = blockIdx.x;
    const int sw = (bid & 7) * 144 + (bid >> 3);     // XCD swizzle (8|1152)
    const int it = sw / 24, jt = sw - it * 24;
    const int i0 = it * 16, j0 = jt * 32;
    const int ti = lane >> 3, tj = lane & 7;

    const int hbase = wv * 256;

    // each wave preloads ITS OWN h-half of w -> no barrier needed
    *(float4*)&wl[t * 4] = *(const float4*)&w[t * 4];

    // staging geometry
    const int arow = lane >> 2;                      // Ea row 0..15
    const int acol = (lane & 3) * 16;
    const int prm  = lane >> 1;                      // Em physical row 0..31
    const int lrm  = (prm & 7) * 4 + (prm >> 3);     // logical j row
    const int mcol = (lane & 1) * 32;

    const float* srcA = &pw[(i0 + arow) * NC + hbase + acol];
    const float* srcM = &pw[(j0 + lrm) * NC + 512 + hbase + mcol];

    float4 fa[4], fm[8];
    #pragma unroll
    for (int q = 0; q < 4; ++q) fa[q] = *(const float4*)(srcA + q * 4);
    #pragma unroll
    for (int q = 0; q < 8; ++q) fm[q] = *(const float4*)(srcM + q * 4);

    float accA0 = 0.f, accA1 = 0.f, accA2 = 0.f, accA3 = 0.f;
    float accB0 = 0.f, accB1 = 0.f, accB2 = 0.f, accB3 = 0.f;

    #pragma unroll 1
    for (int c = 0; c < 4; ++c) {
        const int hh = c * 64;
        #pragma unroll
        for (int q = 0; q < 4; ++q) *(float4*)&EaS[wv][arow][acol + q * 4] = fa[q];
        #pragma unroll
        for (int q = 0; q < 8; ++q) *(float4*)&EmS[wv][prm][mcol + q * 4] = fm[q];
        if (c < 3) {
            #pragma unroll
            for (int q = 0; q < 4; ++q) fa[q] = *(const float4*)(srcA + hh + 64 + q * 4);
            #pragma unroll
            for (int q = 0; q < 8; ++q) fm[q] = *(const float4*)(srcM + hh + 64 + q * 4);
        }
        #pragma unroll
        for (int hq = 0; hq < 16; ++hq) {
            float4 e0 = *(const float4*)&EaS[wv][2 * ti    ][hq * 4];
            float4 e1 = *(const float4*)&EaS[wv][2 * ti + 1][hq * 4];
            float4 f0 = *(const float4*)&EmS[wv][tj        ][hq * 4];
            float4 f1 = *(const float4*)&EmS[wv][tj + 8    ][hq * 4];
            float4 f2 = *(const float4*)&EmS[wv][tj + 16   ][hq * 4];
            float4 f3 = *(const float4*)&EmS[wv][tj + 24   ][hq * 4];
            float4 w4 = *(const float4*)&wl[hbase + hh + hq * 4];   // uniform -> broadcast
            #define PAIR_STEP(EH, FH0, FH1, FH2, FH3, WH)                        \
            {                                                                    \
                {   float e = e0.EH;                                             \
                    float d0 = fmaf(e, FH0, 1.f), d1 = fmaf(e, FH1, 1.f);        \
                    float d2 = fmaf(e, FH2, 1.f), d3 = fmaf(e, FH3, 1.f);        \
                    float d01 = d0 * d1, d23 = d2 * d3;                          \
                    float r = fast_rcp(d01 * d23);                               \
                    float rw = r * WH;                                           \
                    float rw01 = rw * d23, rw23 = rw * d01;                      \
                    accA0 = fmaf(rw01, d1, accA0);                               \
                    accA1 = fmaf(rw01, d0, accA1);                               \
                    accA2 = fmaf(rw23, d3, accA2);                               \
                    accA3 = fmaf(rw23, d2, accA3); }                             \
                {   float e = e1.EH;                                             \
                    float d0 = fmaf(e, FH0, 1.f), d1 = fmaf(e, FH1, 1.f);        \
                    float d2 = fmaf(e, FH2, 1.f), d3 = fmaf(e, FH3, 1.f);        \
                    float d01 = d0 * d1, d23 = d2 * d3;                          \
                    float r = fast_rcp(d01 * d23);                               \
                    float rw = r * WH;                                           \
                    float rw01 = rw * d23, rw23 = rw * d01;                      \
                    accB0 = fmaf(rw01, d1, accB0);                               \
                    accB1 = fmaf(rw01, d0, accB1);                               \
                    accB2 = fmaf(rw23, d3, accB2);                               \
                    accB3 = fmaf(rw23, d2, accB3); }                             \
            }
            PAIR_STEP(x, f0.x, f1.x, f2.x, f3.x, w4.x)
            PAIR_STEP(y, f0.y, f1.y, f2.y, f3.y, w4.y)
            PAIR_STEP(z, f0.z, f1.z, f2.z, f3.z, w4.z)
            PAIR_STEP(w, f0.w, f1.w, f2.w, f3.w, w4.w)
            #undef PAIR_STEP
        }
    }

    // combine the two waves' h-halves (partial overlays EaS -- dead by now)
    float* partial = (float*)EaS;
    __syncthreads();
    if (wv == 1) {
        partial[lane * 8 + 0] = accA0; partial[lane * 8 + 1] = accA1;
        partial[lane * 8 + 2] = accA2; partial[lane * 8 + 3] = accA3;
        partial[lane * 8 + 4] = accB0; partial[lane * 8 + 5] = accB1;
        partial[lane * 8 + 6] = accB2; partial[lane * 8 + 7] = accB3;
    }
    __syncthreads();
    if (wv == 0) {
        float4 wa = *(const float4*)&wl[lane * 8];
        float4 wb = *(const float4*)&wl[lane * 8 + 4];
        float lsum = (wa.x + wa.y) + (wa.z + wa.w) + (wb.x + wb.y) + (wb.z + wb.w);
        #pragma unroll
        for (int d = 1; d < 64; d <<= 1) lsum += __shfl_xor(lsum, d, 64);
        const float base = lsum + outBias[0];
        const int gi = i0 + 2 * ti, gj = j0 + 4 * tj;
        float4 o0, o1;
        o0.x = fmaf(-2.f, accA0 + partial[lane * 8 + 0], base);
        o0.y = fmaf(-2.f, accA1 + partial[lane * 8 + 1], base);
        o0.z = fmaf(-2.f, accA2 + partial[lane * 8 + 2], base);
        o0.w = fmaf(-2.f, accA3 + partial[lane * 8 + 3], base);
        o1.x = fmaf(-2.f, accB0 + partial[lane * 8 + 4], base);
        o1.y = fmaf(-2.f, accB1 + partial[lane * 8 + 5], base);
        o1.z = fmaf(-2.f, accB2 + partial[lane * 8 + 6], base);
        o1.w = fmaf(-2.f, accB3 + partial[lane * 8 + 7], base);
        *(float4*)&out[gi * TT + gj]       = o0;
        *(float4*)&out[(gi + 1) * TT + gj] = o1;
    }
}

extern "C" void kernel_launch(void* const* d_in, const int* in_sizes, int n_in,
                              void* d_out, int out_size, void* d_ws, size_t ws_size,
                              hipStream_t stream) {
    const float* x        = (const float*)d_in[0];
    const float* foh      = (const float*)d_in[1];
    const float* fom      = (const float*)d_in[2];
    const float* catBias  = (const float*)d_in[3];
    const float* hid2     = (const float*)d_in[4];
    const float* hid2Bias = (const float*)d_in[5];
    const float* outLayer = (const float*)d_in[6];
    const float* outBias  = (const float*)d_in[7];
    float* out = (float*)d_out;

    char* wsb = (char*)d_ws;
    float*  pw  = (float*)(wsb);                        // 768*1024*4
    ushort* act = (ushort*)(wsb + 3145728);             // 768*1024*2
    ushort* xb  = (ushort*)(wsb + 4718592);             // 768*512*2
    ushort* b1t = (ushort*)(wsb + 5505024);             // 1024*512*2
    ushort* h2t = (ushort*)(wsb + 6553600);             // 512*1024*2

    k_prep <<<dim3(352),    256, 0, stream>>>(x, foh, fom, hid2, xb, b1t, h2t);
    k_gemm1<<<dim3(16, 12), 256, 0, stream>>>(xb, b1t, catBias, act);
    k_gemm2<<<dim3(16, 12), 256, 0, stream>>>(act, h2t, hid2Bias, pw);
    k_pair <<<dim3(1152),   128, 0, stream>>>(pw, outLayer, outBias, out);
}